// Round 1
// baseline (1159.474 us; speedup 1.0000x reference)
//
#include <hip/hip_runtime.h>
#include <hip/hip_bf16.h>

#define N_NODES 50000
#define N_EDGES 150000
#define F 512
#define BM 128
#define BN 128
#define BK 64

typedef __attribute__((ext_vector_type(4))) float f32x4;
typedef __attribute__((ext_vector_type(4))) unsigned int u32x4;

__device__ __forceinline__ unsigned short f2bf(float f) {
    unsigned int u = __float_as_uint(f);
    return (unsigned short)((u + 0x7fffu + ((u >> 16) & 1u)) >> 16);
}
__device__ __forceinline__ unsigned int pack2(float a, float b) {
    return (unsigned int)f2bf(a) | ((unsigned int)f2bf(b) << 16);
}

// ---- degree accumulation: norms[0..N) = deg_out, norms[N..2N) = deg_in ----
__global__ void __launch_bounds__(256) crd_deg(const int* __restrict__ src,
                                               const int* __restrict__ dst,
                                               float* __restrict__ norms) {
    int e = blockIdx.x * 256 + threadIdx.x;
    if (e < N_EDGES) {
        atomicAdd(&norms[src[e]], 1.0f);
        atomicAdd(&norms[N_NODES + dst[e]], 1.0f);
    }
}

// ---- deg -> rsqrt(max(deg,1)) in place ----
__global__ void __launch_bounds__(256) crd_norm(float* __restrict__ norms) {
    int i = blockIdx.x * 256 + threadIdx.x;
    if (i < 2 * N_NODES) {
        float d = norms[i];
        norms[i] = rsqrtf(d > 0.0f ? d : 1.0f);
    }
}

// ---- Wt[n][k] = bf16(W[k][n]) ----
__global__ void __launch_bounds__(256) crd_wt(const float* __restrict__ W,
                                              unsigned short* __restrict__ Wt) {
    int idx = blockIdx.x * 256 + threadIdx.x;  // idx = n*512 + k
    int n = idx >> 9, k = idx & 511;
    Wt[idx] = f2bf(W[k * F + n]);
}

// ---- agg[dst] += x[src] * norm_src[src] ----
__global__ void __launch_bounds__(256) crd_scatter(const float* __restrict__ x,
                                                   const int* __restrict__ src,
                                                   const int* __restrict__ dst,
                                                   const float* __restrict__ norms,
                                                   float* __restrict__ agg) {
    int t = blockIdx.x * 256 + threadIdx.x;
    int e = t >> 7;             // 128 float4-chunks per edge
    if (e >= N_EDGES) return;
    int f4 = t & 127;
    int s = src[e], d = dst[e];
    float ns = norms[s];
    f32x4 v = *(const f32x4*)(x + (size_t)s * F + f4 * 4);
    float* ap = agg + (size_t)d * F + f4 * 4;
    atomicAdd(ap + 0, v.x * ns);
    atomicAdd(ap + 1, v.y * ns);
    atomicAdd(ap + 2, v.z * ns);
    atomicAdd(ap + 3, v.w * ns);
}

// ---- out = relu((agg * norm_dst) @ W + b), bf16 MFMA ----
// LDS layout: granule(k8,row) = k8*BM + (row ^ k8), 8 bf16 (16B) per granule.
// Fragment (16x16x32 bf16): lane l -> row/col = l&15, k = 8*(l>>4)+{0..7}.
__global__ void __launch_bounds__(256, 2) crd_gemm(const float* __restrict__ agg,
                                                   const unsigned short* __restrict__ Wt,
                                                   const float* __restrict__ norm_dst,
                                                   const float* __restrict__ bias,
                                                   float* __restrict__ out) {
    __shared__ __align__(16) unsigned short lA[8 * BM * 8];
    __shared__ __align__(16) unsigned short lB[8 * BN * 8];
    const int tid = threadIdx.x;
    const int rowbase = blockIdx.x * BM;
    const int nbase = blockIdx.y * BN;
    const int lane = tid & 63;
    const int wave = tid >> 6;
    const int wm = wave >> 1, wn = wave & 1;
    const int g = lane >> 4, r = lane & 15;

    f32x4 zero4 = {0.0f, 0.0f, 0.0f, 0.0f};
    f32x4 acc[4][4];
    #pragma unroll
    for (int i = 0; i < 4; ++i)
        #pragma unroll
        for (int j = 0; j < 4; ++j) acc[i][j] = zero4;

    for (int ks = 0; ks < F / BK; ++ks) {
        // stage A (f32 -> bf16, scaled by norm_dst)
        #pragma unroll
        for (int it = 0; it < 4; ++it) {
            int c = it * 256 + tid;         // 0..1023
            int k8 = c & 7, row = c >> 3;   // row 0..127
            int grow = rowbase + row;
            f32x4 v0 = zero4, v1 = zero4;
            float nd = 0.0f;
            if (grow < N_NODES) {
                const float* p = agg + (size_t)grow * F + ks * BK + k8 * 8;
                v0 = *(const f32x4*)p;
                v1 = *(const f32x4*)(p + 4);
                nd = norm_dst[grow];
            }
            u32x4 w;
            w.x = pack2(v0.x * nd, v0.y * nd);
            w.y = pack2(v0.z * nd, v0.w * nd);
            w.z = pack2(v1.x * nd, v1.y * nd);
            w.w = pack2(v1.z * nd, v1.w * nd);
            *(u32x4*)&lA[(k8 * BM + (row ^ k8)) * 8] = w;
        }
        // stage B (already bf16, from Wt[n][k])
        #pragma unroll
        for (int it = 0; it < 4; ++it) {
            int c = it * 256 + tid;
            int k8 = c & 7, n = c >> 3;     // n 0..127
            u32x4 v = *(const u32x4*)(Wt + (size_t)(nbase + n) * F + ks * BK + k8 * 8);
            *(u32x4*)&lB[(k8 * BN + (n ^ k8)) * 8] = v;
        }
        __syncthreads();
        #pragma unroll
        for (int kk = 0; kk < 2; ++kk) {
            int k8 = kk * 4 + g;
            u32x4 af[4], bfr[4];
            #pragma unroll
            for (int mi = 0; mi < 4; ++mi) {
                int row = wm * 64 + mi * 16 + r;
                af[mi] = *(const u32x4*)&lA[(k8 * BM + (row ^ k8)) * 8];
            }
            #pragma unroll
            for (int ni = 0; ni < 4; ++ni) {
                int n = wn * 64 + ni * 16 + r;
                bfr[ni] = *(const u32x4*)&lB[(k8 * BN + (n ^ k8)) * 8];
            }
            #pragma unroll
            for (int mi = 0; mi < 4; ++mi)
                #pragma unroll
                for (int ni = 0; ni < 4; ++ni)
                    asm("v_mfma_f32_16x16x32_bf16 %0, %1, %2, %0"
                        : "+v"(acc[mi][ni])
                        : "v"(af[mi]), "v"(bfr[ni]));
        }
        __syncthreads();
    }
    // epilogue: D row = g*4+j, col = r
    #pragma unroll
    for (int ni = 0; ni < 4; ++ni) {
        int col = nbase + wn * 64 + ni * 16 + r;
        float bv = bias[col];
        #pragma unroll
        for (int mi = 0; mi < 4; ++mi) {
            #pragma unroll
            for (int j = 0; j < 4; ++j) {
                int row = rowbase + wm * 64 + mi * 16 + g * 4 + j;
                if (row < N_NODES) {
                    float v = acc[mi][ni][j] + bv;
                    out[(size_t)row * F + col] = v > 0.0f ? v : 0.0f;
                }
            }
        }
    }
}

extern "C" void kernel_launch(void* const* d_in, const int* in_sizes, int n_in,
                              void* d_out, int out_size, void* d_ws, size_t ws_size,
                              hipStream_t stream) {
    const float* x = (const float*)d_in[0];
    const int* src = (const int*)d_in[1];
    const int* dst = (const int*)d_in[2];
    const float* W = (const float*)d_in[3];
    const float* bias = (const float*)d_in[4];
    float* out = (float*)d_out;

    const size_t agg_elems = (size_t)N_NODES * F;          // 25.6M floats
    const size_t need = (agg_elems + 2 * N_NODES) * sizeof(float)
                      + (size_t)F * F * sizeof(unsigned short);
    if (ws_size < need) {
        // diagnostic failure mode: zero output -> absmax == ref max
        hipMemsetAsync(d_out, 0, (size_t)out_size * sizeof(float), stream);
        return;
    }

    float* agg = (float*)d_ws;
    float* norms = agg + agg_elems;                        // [deg_out | deg_in] -> norms
    unsigned short* Wt = (unsigned short*)(norms + 2 * N_NODES);

    hipMemsetAsync(agg, 0, (agg_elems + 2 * N_NODES) * sizeof(float), stream);

    crd_deg<<<(N_EDGES + 255) / 256, 256, 0, stream>>>(src, dst, norms);
    crd_norm<<<(2 * N_NODES + 255) / 256, 256, 0, stream>>>(norms);
    crd_wt<<<(F * F) / 256, 256, 0, stream>>>(W, Wt);

    int sth = N_EDGES * 128;  // 19.2M threads
    crd_scatter<<<(sth + 255) / 256, 256, 0, stream>>>(x, src, dst, norms, agg);

    dim3 grid((N_NODES + BM - 1) / BM, F / BN);
    crd_gemm<<<grid, 256, 0, stream>>>(agg, Wt, norms + N_NODES, bias, out);
}

// Round 2
// 280.805 us; speedup vs baseline: 4.1291x; 4.1291x over previous
//
#include <hip/hip_runtime.h>
#include <hip/hip_bf16.h>

#define N_NODES 50000
#define N_PAD   50048   // 391 * 128, zero-padded agg rows so GEMM staging needs no mask
#define N_EDGES 150000
#define F 512
#define BM 128
#define BN 128
#define BK 64

typedef __attribute__((ext_vector_type(4))) float f32x4;
typedef __attribute__((ext_vector_type(4))) unsigned int u32x4;
typedef __attribute__((ext_vector_type(2))) unsigned int u32x2;
typedef __attribute__((ext_vector_type(4))) int i32x4;

__device__ __forceinline__ unsigned short f2bf(float f) {
    unsigned int u = __float_as_uint(f);
    return (unsigned short)((u + 0x7fffu + ((u >> 16) & 1u)) >> 16);
}
__device__ __forceinline__ unsigned int pack2(float a, float b) {
    return (unsigned int)f2bf(a) | ((unsigned int)f2bf(b) << 16);
}
__device__ __forceinline__ void gload16(const void* g, void* l) {
    __builtin_amdgcn_global_load_lds(
        (const __attribute__((address_space(1))) unsigned int*)g,
        (__attribute__((address_space(3))) unsigned int*)l, 16, 0, 0);
}

// ---- int degree histograms: hist[0..N) = deg_out(src), hist[N..2N) = deg_in(dst) ----
__global__ void __launch_bounds__(256) crd_deg(const int* __restrict__ src,
                                               const int* __restrict__ dst,
                                               int* __restrict__ hist) {
    int e = blockIdx.x * 256 + threadIdx.x;
    if (e < N_EDGES) {
        atomicAdd(&hist[src[e]], 1);
        atomicAdd(&hist[N_NODES + dst[e]], 1);
    }
}

// ---- norms[i] = rsqrt(max(deg,1)) ----
__global__ void __launch_bounds__(256) crd_norm(const int* __restrict__ hist,
                                                float* __restrict__ norms) {
    int i = blockIdx.x * 256 + threadIdx.x;
    if (i < 2 * N_NODES) {
        int d = hist[i];
        norms[i] = rsqrtf((float)(d > 0 ? d : 1));
    }
}

// ---- exclusive prefix sum of deg_in -> off[0..N], cursor copy (single block) ----
__global__ void __launch_bounds__(256) crd_scan(const int* __restrict__ hist,
                                                int* __restrict__ off,
                                                int* __restrict__ cursor) {
    __shared__ int s[256];
    const int t = threadIdx.x;
    const int C = 196;                       // ceil(50000/256), divisible by 4
    int lo = t * C;
    int hi = lo + C; if (hi > N_NODES) hi = N_NODES;
    int sum = 0;
    for (int i = lo; i < hi; i += 4) {
        i32x4 v = *(const i32x4*)(hist + i);
        sum += v.x + v.y + v.z + v.w;
    }
    s[t] = sum;
    __syncthreads();
    if (t == 0) {
        int run = 0;
        #pragma unroll 1
        for (int i = 0; i < 256; ++i) { int v = s[i]; s[i] = run; run += v; }
    }
    __syncthreads();
    int run = s[t];
    for (int i = lo; i < hi; ++i) {
        off[i] = run; cursor[i] = run; run += hist[i];
    }
    if (t == 255) off[N_NODES] = run;        // == N_EDGES
}

// ---- place edges into dst-sorted order ----
__global__ void __launch_bounds__(256) crd_place(const int* __restrict__ src,
                                                 const int* __restrict__ dst,
                                                 int* __restrict__ cursor,
                                                 int* __restrict__ sorted) {
    int e = blockIdx.x * 256 + threadIdx.x;
    if (e < N_EDGES) {
        int slot = atomicAdd(&cursor[dst[e]], 1);
        sorted[slot] = src[e];
    }
}

// ---- Wt[n][k] = bf16(W[k][n]) ----
__global__ void __launch_bounds__(256) crd_wt(const float* __restrict__ W,
                                              unsigned short* __restrict__ Wt) {
    int idx = blockIdx.x * 256 + threadIdx.x;  // idx = n*512 + k
    int n = idx >> 9, k = idx & 511;
    Wt[idx] = f2bf(W[k * F + n]);
}

// ---- one wave per dst node: aggb[d] = bf16( norm_dst[d] * sum_e x[src_e]*norm_src ) ----
__global__ void __launch_bounds__(256) crd_gather(const float* __restrict__ x,
                                                  const int* __restrict__ sorted,
                                                  const int* __restrict__ off,
                                                  const float* __restrict__ norms,
                                                  unsigned short* __restrict__ aggb) {
    int wid = (blockIdx.x * 256 + threadIdx.x) >> 6;
    int lane = threadIdx.x & 63;
    if (wid >= N_PAD) return;
    f32x4 a0 = {0.f, 0.f, 0.f, 0.f}, a1 = a0;
    if (wid < N_NODES) {
        int e0 = off[wid], e1 = off[wid + 1];
        for (int e = e0; e < e1; ++e) {
            int s = sorted[e];
            float ns = norms[s];
            const f32x4* p = (const f32x4*)(x + (size_t)s * F);
            a0 += p[lane] * ns;        // floats [lane*4, lane*4+4)
            a1 += p[64 + lane] * ns;   // floats [256+lane*4, ...)
        }
        float nd = norms[N_NODES + wid];
        a0 *= nd; a1 *= nd;
    }
    unsigned short* row = aggb + (size_t)wid * F;
    u32x2 w0, w1;
    w0.x = pack2(a0.x, a0.y); w0.y = pack2(a0.z, a0.w);
    w1.x = pack2(a1.x, a1.y); w1.y = pack2(a1.z, a1.w);
    *(u32x2*)(row + lane * 4) = w0;
    *(u32x2*)(row + 256 + lane * 4) = w1;
}

// ---- out = relu(aggb @ W + b), bf16 MFMA, global_load_lds staging ----
// LDS granule layout: granule(k8,row) at linear index k8*128+row, 8 bf16 (16B) each.
// Fragment (16x16x32 bf16): lane l -> row/col = l&15, k = 8*(l>>4)+{0..7}.
__global__ void __launch_bounds__(256, 3) crd_gemm(const unsigned short* __restrict__ aggb,
                                                   const unsigned short* __restrict__ Wt,
                                                   const float* __restrict__ bias,
                                                   float* __restrict__ out) {
    __shared__ __align__(16) unsigned short lA[8 * BM * 8];
    __shared__ __align__(16) unsigned short lB[8 * BN * 8];
    const int tid = threadIdx.x;
    const int rowbase = blockIdx.x * BM;
    const int nbase = blockIdx.y * BN;
    const int lane = tid & 63;
    const int wave = tid >> 6;
    const int wm = wave >> 1, wn = wave & 1;
    const int g = lane >> 4, r = lane & 15;

    f32x4 zero4 = {0.f, 0.f, 0.f, 0.f};
    f32x4 acc[4][4];
    #pragma unroll
    for (int i = 0; i < 4; ++i)
        #pragma unroll
        for (int j = 0; j < 4; ++j) acc[i][j] = zero4;

    for (int ks = 0; ks < F / BK; ++ks) {
        #pragma unroll
        for (int j = 0; j < 4; ++j) {
            int gg = (wave * 4 + j) * 64 + lane;     // granule id 0..1023
            int k8 = gg >> 7, row = gg & 127;
            gload16(aggb + (size_t)(rowbase + row) * F + ks * BK + k8 * 8,
                    &lA[(size_t)(wave * 4 + j) * 64 * 8]);
        }
        #pragma unroll
        for (int j = 0; j < 4; ++j) {
            int gg = (wave * 4 + j) * 64 + lane;
            int k8 = gg >> 7, n = gg & 127;
            gload16(Wt + (size_t)(nbase + n) * F + ks * BK + k8 * 8,
                    &lB[(size_t)(wave * 4 + j) * 64 * 8]);
        }
        __syncthreads();
        #pragma unroll
        for (int kk = 0; kk < 2; ++kk) {
            int k8 = kk * 4 + g;
            u32x4 af[4], bfr[4];
            #pragma unroll
            for (int mi = 0; mi < 4; ++mi)
                af[mi] = *(const u32x4*)&lA[(k8 * BM + wm * 64 + mi * 16 + r) * 8];
            #pragma unroll
            for (int ni = 0; ni < 4; ++ni)
                bfr[ni] = *(const u32x4*)&lB[(k8 * BN + wn * 64 + ni * 16 + r) * 8];
            #pragma unroll
            for (int mi = 0; mi < 4; ++mi)
                #pragma unroll
                for (int ni = 0; ni < 4; ++ni)
                    asm("v_mfma_f32_16x16x32_bf16 %0, %1, %2, %0"
                        : "+v"(acc[mi][ni])
                        : "v"(af[mi]), "v"(bfr[ni]));
        }
        __syncthreads();
    }
    #pragma unroll
    for (int ni = 0; ni < 4; ++ni) {
        int col = nbase + wn * 64 + ni * 16 + r;
        float bv = bias[col];
        #pragma unroll
        for (int mi = 0; mi < 4; ++mi) {
            #pragma unroll
            for (int j = 0; j < 4; ++j) {
                int row = rowbase + wm * 64 + mi * 16 + g * 4 + j;
                if (row < N_NODES) {
                    float v = acc[mi][ni][j] + bv;
                    out[(size_t)row * F + col] = v > 0.0f ? v : 0.0f;
                }
            }
        }
    }
}

extern "C" void kernel_launch(void* const* d_in, const int* in_sizes, int n_in,
                              void* d_out, int out_size, void* d_ws, size_t ws_size,
                              hipStream_t stream) {
    const float* x = (const float*)d_in[0];
    const int* src = (const int*)d_in[1];
    const int* dst = (const int*)d_in[2];
    const float* W = (const float*)d_in[3];
    const float* bias = (const float*)d_in[4];
    float* out = (float*)d_out;

    unsigned short* aggb = (unsigned short*)d_ws;               // N_PAD * F bf16
    unsigned short* Wt = aggb + (size_t)N_PAD * F;              // F * F bf16
    float* norms = (float*)(Wt + (size_t)F * F);                // 2N f32
    int* hist = (int*)(norms + 2 * N_NODES);                    // 2N int
    int* off = hist + 2 * N_NODES;                              // N+1 int
    int* cursor = off + N_NODES + 1;                            // N int
    int* sorted = cursor + N_NODES;                             // E int
    size_t need = (size_t)((char*)(sorted + N_EDGES) - (char*)d_ws);
    if (ws_size < need) {
        hipMemsetAsync(d_out, 0, (size_t)out_size * sizeof(float), stream);
        return;
    }

    hipMemsetAsync(hist, 0, 2 * N_NODES * sizeof(int), stream);
    crd_deg<<<(N_EDGES + 255) / 256, 256, 0, stream>>>(src, dst, hist);
    crd_norm<<<(2 * N_NODES + 255) / 256, 256, 0, stream>>>(hist, norms);
    crd_scan<<<1, 256, 0, stream>>>(hist + N_NODES, off, cursor);
    crd_wt<<<(F * F) / 256, 256, 0, stream>>>(W, Wt);
    crd_place<<<(N_EDGES + 255) / 256, 256, 0, stream>>>(src, dst, cursor, sorted);
    crd_gather<<<N_PAD / 4, 256, 0, stream>>>(x, sorted, off, norms, aggb);

    dim3 grid(N_PAD / BM, F / BN);   // 391 x 4
    crd_gemm<<<grid, 256, 0, stream>>>(aggb, Wt, bias, out);
}

// Round 3
// 186.098 us; speedup vs baseline: 6.2305x; 1.5089x over previous
//
#include <hip/hip_runtime.h>
#include <hip/hip_bf16.h>

#define N_NODES 50000
#define N_PAD   50048   // 391 * 128
#define N_EDGES 150000
#define F 512
#define BM 128
#define BN 128
#define BK 64
#define NBLK 196        // ceil(50000/256)

typedef __attribute__((ext_vector_type(4))) float f32x4;
typedef __attribute__((ext_vector_type(4))) unsigned int u32x4;
typedef __attribute__((ext_vector_type(2))) unsigned int u32x2;

__device__ __forceinline__ unsigned short f2bf(float f) {
    unsigned int u = __float_as_uint(f);
    return (unsigned short)((u + 0x7fffu + ((u >> 16) & 1u)) >> 16);
}
__device__ __forceinline__ unsigned int pack2(float a, float b) {
    return (unsigned int)f2bf(a) | ((unsigned int)f2bf(b) << 16);
}
__device__ __forceinline__ void gload16(const void* g, void* l) {
    __builtin_amdgcn_global_load_lds(
        (const __attribute__((address_space(1))) unsigned int*)g,
        (__attribute__((address_space(3))) unsigned int*)l, 16, 0, 0);
}

// ---- degree histograms: hist[0..N)=deg_out(src), hist[N..2N)=deg_in(dst) ----
__global__ void __launch_bounds__(256) crd_deg(const int* __restrict__ src,
                                               const int* __restrict__ dst,
                                               int* __restrict__ hist) {
    int e = blockIdx.x * 256 + threadIdx.x;
    if (e < N_EDGES) {
        atomicAdd(&hist[src[e]], 1);
        atomicAdd(&hist[N_NODES + dst[e]], 1);
    }
}

__global__ void __launch_bounds__(256) crd_norm(const int* __restrict__ hist,
                                                float* __restrict__ norms) {
    int i = blockIdx.x * 256 + threadIdx.x;
    if (i < 2 * N_NODES) {
        int d = hist[i];
        norms[i] = rsqrtf((float)(d > 0 ? d : 1));
    }
}

// ---- hierarchical exclusive scan of deg_in ----
__global__ void __launch_bounds__(256) crd_bsum(const int* __restrict__ hist_in,
                                                int* __restrict__ bsum) {
    __shared__ int s[256];
    int t = threadIdx.x;
    int i = blockIdx.x * 256 + t;
    s[t] = (i < N_NODES) ? hist_in[i] : 0;
    __syncthreads();
    #pragma unroll
    for (int o = 128; o > 0; o >>= 1) {
        if (t < o) s[t] += s[t + o];
        __syncthreads();
    }
    if (t == 0) bsum[blockIdx.x] = s[0];
}

__global__ void __launch_bounds__(256) crd_bscan(const int* __restrict__ bsum,
                                                 int* __restrict__ bsumoff) {
    __shared__ int s[256];
    int t = threadIdx.x;
    int v = (t < NBLK) ? bsum[t] : 0;
    s[t] = v;
    __syncthreads();
    #pragma unroll
    for (int d = 1; d < 256; d <<= 1) {
        int add = (t >= d) ? s[t - d] : 0;
        __syncthreads();
        s[t] += add;
        __syncthreads();
    }
    if (t < NBLK) bsumoff[t] = s[t] - v;   // exclusive
}

__global__ void __launch_bounds__(256) crd_escan(const int* __restrict__ hist_in,
                                                 const int* __restrict__ bsumoff,
                                                 int* __restrict__ off,
                                                 int* __restrict__ cursor) {
    __shared__ int s[256];
    int t = threadIdx.x;
    int i = blockIdx.x * 256 + t;
    int v = (i < N_NODES) ? hist_in[i] : 0;
    s[t] = v;
    __syncthreads();
    #pragma unroll
    for (int d = 1; d < 256; d <<= 1) {
        int add = (t >= d) ? s[t - d] : 0;
        __syncthreads();
        s[t] += add;
        __syncthreads();
    }
    int excl = s[t] - v + bsumoff[blockIdx.x];
    if (i < N_NODES) { off[i] = excl; cursor[i] = excl; }
    if (i == N_NODES - 1) off[N_NODES] = excl + v;
}

// ---- place edges into dst-sorted order ----
__global__ void __launch_bounds__(256) crd_place(const int* __restrict__ src,
                                                 const int* __restrict__ dst,
                                                 int* __restrict__ cursor,
                                                 int* __restrict__ sorted) {
    int e = blockIdx.x * 256 + threadIdx.x;
    if (e < N_EDGES) {
        int slot = atomicAdd(&cursor[dst[e]], 1);
        sorted[slot] = src[e];
    }
}

// ---- Wt[n][k] = bf16(W[k][n]) ----
__global__ void __launch_bounds__(256) crd_wt(const float* __restrict__ W,
                                              unsigned short* __restrict__ Wt) {
    int idx = blockIdx.x * 256 + threadIdx.x;
    int n = idx >> 9, k = idx & 511;
    Wt[idx] = f2bf(W[k * F + n]);
}

// ---- xb = bf16(x), 8 elems/thread ----
__global__ void __launch_bounds__(256) crd_xb(const float* __restrict__ x,
                                              unsigned short* __restrict__ xb) {
    size_t i = (size_t)(blockIdx.x * 256 + threadIdx.x) * 8;
    f32x4 v0 = *(const f32x4*)(x + i);
    f32x4 v1 = *(const f32x4*)(x + i + 4);
    u32x4 w;
    w.x = pack2(v0.x, v0.y); w.y = pack2(v0.z, v0.w);
    w.z = pack2(v1.x, v1.y); w.w = pack2(v1.z, v1.w);
    *(u32x4*)(xb + i) = w;
}

// ---- one wave per dst node, bf16 x path ----
__global__ void __launch_bounds__(256) crd_gather_bf(const unsigned short* __restrict__ xb,
                                                     const int* __restrict__ sorted,
                                                     const int* __restrict__ off,
                                                     const float* __restrict__ norms,
                                                     unsigned short* __restrict__ aggb) {
    int wid = (blockIdx.x * 256 + threadIdx.x) >> 6;
    int lane = threadIdx.x & 63;
    if (wid >= N_PAD) return;
    float a0=0.f,a1=0.f,a2=0.f,a3=0.f,a4=0.f,a5=0.f,a6=0.f,a7=0.f;
    if (wid < N_NODES) {
        int e0 = off[wid], e1 = off[wid + 1];
        for (int e = e0; e < e1; ++e) {
            int s = sorted[e];
            float ns = norms[s];
            u32x4 v = *(const u32x4*)(xb + (size_t)s * F + lane * 8);
            a0 += __uint_as_float(v.x << 16) * ns;
            a1 += __uint_as_float(v.x & 0xffff0000u) * ns;
            a2 += __uint_as_float(v.y << 16) * ns;
            a3 += __uint_as_float(v.y & 0xffff0000u) * ns;
            a4 += __uint_as_float(v.z << 16) * ns;
            a5 += __uint_as_float(v.z & 0xffff0000u) * ns;
            a6 += __uint_as_float(v.w << 16) * ns;
            a7 += __uint_as_float(v.w & 0xffff0000u) * ns;
        }
        float nd = norms[N_NODES + wid];
        a0*=nd;a1*=nd;a2*=nd;a3*=nd;a4*=nd;a5*=nd;a6*=nd;a7*=nd;
    }
    u32x4 w;
    w.x = pack2(a0, a1); w.y = pack2(a2, a3);
    w.z = pack2(a4, a5); w.w = pack2(a6, a7);
    *(u32x4*)(aggb + (size_t)wid * F + lane * 8) = w;
}

// ---- fallback: f32 x path (if ws too small for xb) ----
__global__ void __launch_bounds__(256) crd_gather_f32(const float* __restrict__ x,
                                                      const int* __restrict__ sorted,
                                                      const int* __restrict__ off,
                                                      const float* __restrict__ norms,
                                                      unsigned short* __restrict__ aggb) {
    int wid = (blockIdx.x * 256 + threadIdx.x) >> 6;
    int lane = threadIdx.x & 63;
    if (wid >= N_PAD) return;
    f32x4 a0 = {0.f,0.f,0.f,0.f}, a1 = a0;
    if (wid < N_NODES) {
        int e0 = off[wid], e1 = off[wid + 1];
        for (int e = e0; e < e1; ++e) {
            int s = sorted[e];
            float ns = norms[s];
            const f32x4* p = (const f32x4*)(x + (size_t)s * F);
            a0 += p[lane] * ns;
            a1 += p[64 + lane] * ns;
        }
        float nd = norms[N_NODES + wid];
        a0 *= nd; a1 *= nd;
    }
    unsigned short* row = aggb + (size_t)wid * F;
    u32x2 w0, w1;
    w0.x = pack2(a0.x, a0.y); w0.y = pack2(a0.z, a0.w);
    w1.x = pack2(a1.x, a1.y); w1.y = pack2(a1.z, a1.w);
    *(u32x2*)(row + lane * 4) = w0;
    *(u32x2*)(row + 256 + lane * 4) = w1;
}

// ---- out = relu(aggb @ W + b), bf16 MFMA, global_load_lds staging ----
__global__ void __launch_bounds__(256, 3) crd_gemm(const unsigned short* __restrict__ aggb,
                                                   const unsigned short* __restrict__ Wt,
                                                   const float* __restrict__ bias,
                                                   float* __restrict__ out) {
    __shared__ __align__(16) unsigned short lA[8 * BM * 8];
    __shared__ __align__(16) unsigned short lB[8 * BN * 8];
    const int tid = threadIdx.x;
    const int rowbase = blockIdx.x * BM;
    const int nbase = blockIdx.y * BN;
    const int lane = tid & 63;
    const int wave = tid >> 6;
    const int wm = wave >> 1, wn = wave & 1;
    const int g = lane >> 4, r = lane & 15;

    f32x4 zero4 = {0.f, 0.f, 0.f, 0.f};
    f32x4 acc[4][4];
    #pragma unroll
    for (int i = 0; i < 4; ++i)
        #pragma unroll
        for (int j = 0; j < 4; ++j) acc[i][j] = zero4;

    for (int ks = 0; ks < F / BK; ++ks) {
        #pragma unroll
        for (int j = 0; j < 4; ++j) {
            int gg = (wave * 4 + j) * 64 + lane;
            int k8 = gg >> 7, row = gg & 127;
            gload16(aggb + (size_t)(rowbase + row) * F + ks * BK + k8 * 8,
                    &lA[(size_t)(wave * 4 + j) * 64 * 8]);
        }
        #pragma unroll
        for (int j = 0; j < 4; ++j) {
            int gg = (wave * 4 + j) * 64 + lane;
            int k8 = gg >> 7, n = gg & 127;
            gload16(Wt + (size_t)(nbase + n) * F + ks * BK + k8 * 8,
                    &lB[(size_t)(wave * 4 + j) * 64 * 8]);
        }
        __syncthreads();
        #pragma unroll
        for (int kk = 0; kk < 2; ++kk) {
            int k8 = kk * 4 + g;
            u32x4 af[4], bfr[4];
            #pragma unroll
            for (int mi = 0; mi < 4; ++mi)
                af[mi] = *(const u32x4*)&lA[(k8 * BM + wm * 64 + mi * 16 + r) * 8];
            #pragma unroll
            for (int ni = 0; ni < 4; ++ni)
                bfr[ni] = *(const u32x4*)&lB[(k8 * BN + wn * 64 + ni * 16 + r) * 8];
            #pragma unroll
            for (int mi = 0; mi < 4; ++mi)
                #pragma unroll
                for (int ni = 0; ni < 4; ++ni)
                    asm("v_mfma_f32_16x16x32_bf16 %0, %1, %2, %0"
                        : "+v"(acc[mi][ni])
                        : "v"(af[mi]), "v"(bfr[ni]));
        }
        __syncthreads();
    }
    #pragma unroll
    for (int ni = 0; ni < 4; ++ni) {
        int col = nbase + wn * 64 + ni * 16 + r;
        float bv = bias[col];
        #pragma unroll
        for (int mi = 0; mi < 4; ++mi) {
            #pragma unroll
            for (int j = 0; j < 4; ++j) {
                int row = rowbase + wm * 64 + mi * 16 + g * 4 + j;
                if (row < N_NODES) {
                    float v = acc[mi][ni][j] + bv;
                    out[(size_t)row * F + col] = v > 0.0f ? v : 0.0f;
                }
            }
        }
    }
}

extern "C" void kernel_launch(void* const* d_in, const int* in_sizes, int n_in,
                              void* d_out, int out_size, void* d_ws, size_t ws_size,
                              hipStream_t stream) {
    const float* x = (const float*)d_in[0];
    const int* src = (const int*)d_in[1];
    const int* dst = (const int*)d_in[2];
    const float* W = (const float*)d_in[3];
    const float* bias = (const float*)d_in[4];
    float* out = (float*)d_out;

    unsigned short* aggb = (unsigned short*)d_ws;               // N_PAD*F bf16
    unsigned short* Wt = aggb + (size_t)N_PAD * F;              // F*F bf16
    float* norms = (float*)(Wt + (size_t)F * F);                // 2N f32
    int* hist = (int*)(norms + 2 * N_NODES);                    // 2N int
    int* off = hist + 2 * N_NODES;                              // N+1 int
    int* cursor = off + N_NODES + 1;                            // N int
    int* sorted = cursor + N_NODES;                             // E int
    int* bsum = sorted + N_EDGES;                               // NBLK int
    int* bsumoff = bsum + NBLK;                                 // NBLK int
    char* endp = (char*)(bsumoff + NBLK);
    // 64B-align xb
    unsigned short* xb = (unsigned short*)(((uintptr_t)endp + 63) & ~(uintptr_t)63);
    size_t need_min = (size_t)(endp - (char*)d_ws);
    size_t need_bf = (size_t)((char*)(xb + (size_t)N_NODES * F) - (char*)d_ws);
    if (ws_size < need_min) {
        hipMemsetAsync(d_out, 0, (size_t)out_size * sizeof(float), stream);
        return;
    }
    const bool use_bf = (ws_size >= need_bf);

    hipMemsetAsync(hist, 0, 2 * N_NODES * sizeof(int), stream);
    crd_deg<<<(N_EDGES + 255) / 256, 256, 0, stream>>>(src, dst, hist);
    crd_norm<<<(2 * N_NODES + 255) / 256, 256, 0, stream>>>(hist, norms);
    crd_bsum<<<NBLK, 256, 0, stream>>>(hist + N_NODES, bsum);
    crd_bscan<<<1, 256, 0, stream>>>(bsum, bsumoff);
    crd_escan<<<NBLK, 256, 0, stream>>>(hist + N_NODES, bsumoff, off, cursor);
    crd_wt<<<(F * F) / 256, 256, 0, stream>>>(W, Wt);
    crd_place<<<(N_EDGES + 255) / 256, 256, 0, stream>>>(src, dst, cursor, sorted);
    if (use_bf) {
        crd_xb<<<(int)(((size_t)N_NODES * F / 8) / 256), 256, 0, stream>>>(x, xb);
        crd_gather_bf<<<N_PAD / 4, 256, 0, stream>>>(xb, sorted, off, norms, aggb);
    } else {
        crd_gather_f32<<<N_PAD / 4, 256, 0, stream>>>(x, sorted, off, norms, aggb);
    }
    dim3 grid(N_PAD / BM, F / BN);   // 391 x 4
    crd_gemm<<<grid, 256, 0, stream>>>(aggb, Wt, bias, out);
}